// Round 10
// baseline (515.764 us; speedup 1.0000x reference)
//
#include <hip/hip_runtime.h>
#include <stdint.h>

// RNN ensemble: M=2048 models, N=128, A=4 conds, 5 phases x 50 steps.
// Block = 1 model, 4 waves. Wave w owns rows 32w..32w+31 (2 M-tiles).
// pre[128x4] = W @ r via mfma_f32_16x16x32_bf16, hi/lo bf16 split:
//   B cols 0-3 = rhi (4 conds), cols 4-7 = rlo.
// R10: FOUR independent 4-deep MFMA chains (h{t2}=Whi@B, l{t2}=Wlo@B),
// consuming B[q] per-q so only ~1-2 B frags are live (arch VGPR < 64 ->
// no scratch spill, 4 waves/EU). Heads: h = whi@B + ccv (lohalf-masked,
// carries bias+input once), l = wlo@B + 0 (inline literal, no init movs).
// pre = (h+l)[col c] + (h+l)[col c^4] via shfl_xor(4).
// All 16 W frags pinned in AGPRs (exactly 64). Threefry (sub=0) or s_nops
// (sub=1) cover the asm-MFMA -> VALU read hazard window.

typedef __attribute__((ext_vector_type(8))) short bf16x8;
typedef __attribute__((ext_vector_type(4))) float f32x4;

struct __align__(16) Smem {
  unsigned short bfrag[2][4][4][8][8]; // [parity][q][kg][col][e] bf16, 4KB
  float nbuf[2][128];                  // [substep][row] 0.02-scaled noise, 1KB
  uint2 skeys[250];
  float red[4][4][2];                  // [wave][cond][o]
};

__device__ __forceinline__ void tfround(uint32_t& x0, uint32_t& x1, const int r) {
  x0 += x1;
  x1 = (x1 << r) | (x1 >> (32 - r));
  x1 ^= x0;
}

// JAX threefry2x32 (20 rounds)
__device__ __forceinline__ uint2 threefry(uint32_t k0, uint32_t k1, uint32_t c0, uint32_t c1) {
  uint32_t k2 = k0 ^ k1 ^ 0x1BD11BDAu;
  uint32_t x0 = c0 + k0, x1 = c1 + k1;
  tfround(x0,x1,13); tfround(x0,x1,15); tfround(x0,x1,26); tfround(x0,x1,6);
  x0 += k1; x1 += k2 + 1u;
  tfround(x0,x1,17); tfround(x0,x1,29); tfround(x0,x1,16); tfround(x0,x1,24);
  x0 += k2; x1 += k0 + 2u;
  tfround(x0,x1,13); tfround(x0,x1,15); tfround(x0,x1,26); tfround(x0,x1,6);
  x0 += k0; x1 += k1 + 3u;
  tfround(x0,x1,17); tfround(x0,x1,29); tfround(x0,x1,16); tfround(x0,x1,24);
  x0 += k1; x1 += k2 + 4u;
  tfround(x0,x1,13); tfround(x0,x1,15); tfround(x0,x1,26); tfround(x0,x1,6);
  x0 += k2; x1 += k0 + 5u;
  return make_uint2(x0, x1);
}

__device__ __forceinline__ float unit_from_bits(uint32_t bits) {
  return __uint_as_float((bits >> 9) | 0x3f800000u) - 1.0f;
}

__device__ __forceinline__ unsigned short f2bf(float f) {
  uint32_t u = __float_as_uint(f);
  uint32_t r = u + 0x7fffu + ((u >> 16) & 1u);   // RNE (non-NaN inputs)
  return (unsigned short)(r >> 16);
}
__device__ __forceinline__ float bf2f(unsigned short b) {
  return __uint_as_float(((uint32_t)b) << 16);
}
// packed f32x2 -> bf16x2 (D[15:0]=bf16(a), D[31:16]=bf16(b))
__device__ __forceinline__ uint32_t cvt_pk_bf16(float a, float b) {
  uint32_t r;
  asm("v_cvt_pk_bf16_f32 %0, %1, %2" : "=v"(r) : "v"(a), "v"(b));
  return r;
}
// MFMA accumulate in place, A from AGPR.
__device__ __forceinline__ void mfma_aa(f32x4& acc, const bf16x8& a, const bf16x8& b) {
  asm("v_mfma_f32_16x16x32_bf16 %0, %1, %2, %0" : "+v"(acc) : "a"(a), "v"(b));
}
// Chain head: D = A*B + C (D fresh, no init movs).
__device__ __forceinline__ f32x4 mfma_c(const bf16x8& a, const bf16x8& b, const f32x4& c) {
  f32x4 d;
  asm("v_mfma_f32_16x16x32_bf16 %0, %1, %2, %3" : "=&v"(d) : "a"(a), "v"(b), "v"(c));
  return d;
}
// Chain head: D = A*B + 0 (inline-constant C).
__device__ __forceinline__ f32x4 mfma_z(const bf16x8& a, const bf16x8& b) {
  f32x4 d;
  asm("v_mfma_f32_16x16x32_bf16 %0, %1, %2, 0" : "=&v"(d) : "a"(a), "v"(b));
  return d;
}

__global__ __launch_bounds__(256)
__attribute__((amdgpu_waves_per_eu(4, 4)))
void rnn_kernel(
    const float* __restrict__ x,
    const float* __restrict__ rec_w,
    const float* __restrict__ rec_b,
    const float* __restrict__ inp_w,
    const float* __restrict__ out_w,
    const float* __restrict__ mem_w,
    float* __restrict__ out) {
  __shared__ Smem sm;
  const int t = threadIdx.x;
  const int m = blockIdx.x;
  const int w = t >> 6;          // wave 0..3
  const int lane = t & 63;
  const int n = lane & 15;       // A-row / B-col / C-col index within tile
  const int kg = lane >> 4;      // k-group (0..3)
  const int c = n & 3;           // cond id
  const int t2sel = n >> 3;      // owned M-tile (0: rows +0..15, 1: +16..31)
  const int lohalf = (n >> 2) & 1;  // 0 = hi-fragment writer, 1 = lo writer

  // step keys
  if (t < 250) {
    int p = t / 50, s = t - p * 50;
    uint2 pk = threefry(0u, 42u, 0u, (uint32_t)p);
    sm.skeys[t] = threefry(pk.x, pk.y, 0u, (uint32_t)s);
  }
  // zero the fragment buffer: exactly 4KB = 256 threads x 16B
  {
    uint4* bz = reinterpret_cast<uint4*>(&sm.bfrag[0][0][0][0][0]);
    bz[t] = make_uint4(0u, 0u, 0u, 0u);
  }

  // --- W fragments (all AGPR-destined): row = 32w+16*t2+n, k = 32q+8kg+e
  bf16x8 whiA[2][4], wloA[2][4];
  #pragma unroll
  for (int t2 = 0; t2 < 2; ++t2) {
    const int rowA = 32 * w + 16 * t2 + n;
    const float* gp = rec_w + (size_t)m * 16384 + (size_t)rowA * 128 + 8 * kg;
    #pragma unroll
    for (int q = 0; q < 4; ++q) {
      float4 f0 = *reinterpret_cast<const float4*>(gp + 32 * q);
      float4 f1 = *reinterpret_cast<const float4*>(gp + 32 * q + 4);
      float fv[8] = {f0.x, f0.y, f0.z, f0.w, f1.x, f1.y, f1.z, f1.w};
      bf16x8 vh, vl;
      #pragma unroll
      for (int e = 0; e < 8; ++e) {
        unsigned short hb = f2bf(fv[e]);
        vh[e] = (short)hb;
        vl[e] = (short)f2bf(fv[e] - bf2f(hb));
      }
      whiA[t2][q] = vh;
      wloA[t2][q] = vl;
    }
  }

  // per-lane x scalars (cond = c)
  const float xs0 = x[c * 4 + 0], xs1 = x[c * 4 + 1];
  const float xt0 = x[c * 4 + 2], xt1 = x[c * 4 + 3];

  // owned rows: rowU..rowU+3 (cond c)
  const int rowU = 32 * w + 4 * kg + 16 * t2sel;

  float rr[4] = {0.f, 0.f, 0.f, 0.f};
  float rs[4];

  __syncthreads();

  const uint32_t njbase = (uint32_t)(m * 128 + 32 * w + (lane & 31));

  for (int ph = 0; ph < 5; ++ph) {
    // ccv = (bias + input drive) for owned rows, hi lanes only (seeds the
    // h-chain head, so the hi+lo column-pair sum carries cc exactly once).
    f32x4 ccv;
    {
      float4 b4 = *reinterpret_cast<const float4*>(&rec_b[(size_t)m * 128 + rowU]);
      float cc[4] = {b4.x, b4.y, b4.z, b4.w};
      if (ph == 1 || ph == 3) {
        const float xa = (ph == 1) ? xs0 : xt0;
        const float xb = (ph == 1) ? xs1 : xt1;
        const float* ip = inp_w + ((size_t)m * 128 + rowU) * 2;
        float4 iA = *reinterpret_cast<const float4*>(ip);
        float4 iB = *reinterpret_cast<const float4*>(ip + 4);
        cc[0] += iA.x * xa + iA.y * xb;
        cc[1] += iA.z * xa + iA.w * xb;
        cc[2] += iB.x * xa + iB.y * xb;
        cc[3] += iB.z * xa + iB.w * xb;
      }
      #pragma unroll
      for (int k = 0; k < 4; ++k) ccv[k] = lohalf ? 0.f : cc[k];
    }
    const bool phD = (ph == 2), phR = (ph == 4);
    #pragma unroll
    for (int k = 0; k < 4; ++k) rs[k] = 0.f;

    for (int sp = 0; sp < 25; ++sp) {
      #pragma unroll
      for (int sub = 0; sub < 2; ++sub) {
        // --- 4 independent 4-deep MFMA chains; B[q] consumed per-q so at
        // most ~2 B fragments are live (keeps arch VGPR under the 64 cap).
        const unsigned short* bp = &sm.bfrag[sub][0][kg][n & 7][0];
        bf16x8 Bq = *reinterpret_cast<const bf16x8*>(bp);
        f32x4 h0 = mfma_c(whiA[0][0], Bq, ccv);
        f32x4 h1 = mfma_c(whiA[1][0], Bq, ccv);
        f32x4 l0 = mfma_z(wloA[0][0], Bq);
        f32x4 l1 = mfma_z(wloA[1][0], Bq);
        #pragma unroll
        for (int q = 1; q < 4; ++q) {
          Bq = *reinterpret_cast<const bf16x8*>(bp + q * 256);  // [q] stride
          mfma_aa(h0, whiA[0][q], Bq);
          mfma_aa(h1, whiA[1][q], Bq);
          mfma_aa(l0, wloA[0][q], Bq);
          mfma_aa(l1, wloA[1][q], Bq);
        }

        if (sub == 0) {
          // threefry fills the MFMA->read hazard window (~70 VALU instrs) and
          // overlaps the MFMA pipe. nbuf is wave-local; DS ops within a wave
          // are in-order, so the b128 reads below see these writes.
          uint2 key = sm.skeys[ph * 50 + 2 * sp + (lane >> 5)];
          uint2 bb = threefry(key.x, key.y, 0u, njbase);
          sm.nbuf[lane >> 5][32 * w + (lane & 31)] = 0.02f * unit_from_bits(bb.x ^ bb.y);
        } else {
          // inline-asm MFMA is invisible to the hazard recognizer: guard the
          // D->VALU read with explicit wait states.
          asm volatile("s_nop 7\n\ts_nop 3" ::);
        }

        // --- pre = (h+l)[col c] + (h+l)[col c^4]  (carries cc exactly once)
        float4 nz4 = *reinterpret_cast<const float4*>(&sm.nbuf[sub][rowU]);
        float nzv[4] = {nz4.x, nz4.y, nz4.z, nz4.w};
        #pragma unroll
        for (int k = 0; k < 4; ++k) {
          float hk = t2sel ? h1[k] : h0[k];
          float lk = t2sel ? l1[k] : l0[k];
          float s = hk + lk;
          float pre = s + __shfl_xor(s, 4, 64);
          float rl = fmaxf(pre, 0.f);
          rr[k] = fmaf(0.8f, rr[k], fmaf(0.2f, rl, nzv[k]));
        }
        if ((phD && ((sub == 0 && sp >= 13) || (sub == 1 && sp >= 12))) || phR) {
          #pragma unroll
          for (int k = 0; k < 4; ++k) rs[k] += rr[k];
        }

        // --- split & write next-step fragment: every lane writes one uint2.
        {
          const int kgw = 2 * t2sel + (kg >> 1);
          const int e0 = 4 * (kg & 1);
          const int col = c + 4 * lohalf;
          uint32_t h0p = cvt_pk_bf16(rr[0], rr[1]);
          uint32_t h1p = cvt_pk_bf16(rr[2], rr[3]);
          uint2 pk2;
          if (!lohalf) {
            pk2 = make_uint2(h0p, h1p);
          } else {
            float l0v = rr[0] - __uint_as_float(h0p << 16);
            float l1v = rr[1] - __uint_as_float(h0p & 0xffff0000u);
            float l2v = rr[2] - __uint_as_float(h1p << 16);
            float l3v = rr[3] - __uint_as_float(h1p & 0xffff0000u);
            pk2 = make_uint2(cvt_pk_bf16(l0v, l1v), cvt_pk_bf16(l2v, l3v));
          }
          *reinterpret_cast<uint2*>(&sm.bfrag[sub ^ 1][w][kgw][col][e0]) = pk2;
        }
        __syncthreads();
      }
    }

    // --- phase-end projection (linear => project accumulated sums once)
    if (ph == 2 || ph == 4) {
      const float* pw = (ph == 2) ? mem_w : out_w;
      const float denom = (ph == 2) ? 25.0f : 50.0f;
      const int sel = (ph == 2) ? 0 : 1;
      float part[2];
      #pragma unroll
      for (int o = 0; o < 2; ++o) {
        float4 w4 = *reinterpret_cast<const float4*>(&pw[((size_t)m * 2 + o) * 128 + rowU]);
        part[o] = w4.x * rs[0] + w4.y * rs[1] + w4.z * rs[2] + w4.w * rs[3];
      }
      // reduce: xor8 merges t2 partners; xor16/32 merge kg. n&7 classes stay
      // separate, so hi/lo duplicate lanes never double-count.
      #pragma unroll
      for (int o = 0; o < 2; ++o) {
        part[o] += __shfl_xor(part[o], 8, 64);
        part[o] += __shfl_xor(part[o], 16, 64);
        part[o] += __shfl_xor(part[o], 32, 64);
      }
      if (lane < 4) {
        sm.red[w][lane][0] = part[0];
        sm.red[w][lane][1] = part[1];
      }
      __syncthreads();
      if (t < 8) {
        int a = t >> 1, o = t & 1;
        float v = sm.red[0][a][o] + sm.red[1][a][o] + sm.red[2][a][o] + sm.red[3][a][o];
        out[(((size_t)sel * 4 + a) * 2048 + m) * 2 + o] = v / denom;
      }
      __syncthreads();
    }
  }
}

extern "C" void kernel_launch(void* const* d_in, const int* in_sizes, int n_in,
                              void* d_out, int out_size, void* d_ws, size_t ws_size,
                              hipStream_t stream) {
  (void)in_sizes; (void)n_in; (void)d_ws; (void)ws_size; (void)out_size;
  const float* x     = (const float*)d_in[0];
  const float* rec_w = (const float*)d_in[1];
  const float* rec_b = (const float*)d_in[2];
  const float* inp_w = (const float*)d_in[3];
  const float* out_w = (const float*)d_in[4];
  const float* mem_w = (const float*)d_in[5];
  rnn_kernel<<<2048, 256, 0, stream>>>(x, rec_w, rec_b, inp_w, out_w, mem_w, (float*)d_out);
}

// Round 11
// 343.334 us; speedup vs baseline: 1.5022x; 1.5022x over previous
//
#include <hip/hip_runtime.h>
#include <stdint.h>

// RNN ensemble: M=2048 models, N=128, A=4 conds, 5 phases x 50 steps.
// Block = 1 model, 4 waves. Wave w owns rows 32w..32w+31 (2 M-tiles).
// R11: SINGLE-PASS FP16 matvec (halves MFMA count vs bf16 hi/lo split):
//   pre[128x4] = W@r via v_mfma_f32_16x16x32_f16, B cols 0-3 = r (4 conds),
//   fp32 accumulate, cc (bias+input) seeded in the MFMA C-init.
//   Error budget: fp16 W quantization ~1e-6 avg/entry -> r-error ~3e-5 via
//   contractive dynamics; measured absmax floor was reorder-dominated 3e-5,
//   threshold 3.5e-4 -> ~2-3x margin expected.
// 8 W fragments (fp16) pinned in AGPRs (32) via all-asm MFMA; 2 independent
// 4-deep chains (one per M-tile). No hi/lo shfl combine; pre = acc directly.
// Lanes n<4 / 8<=n<12 write next-step B fragments (32 writers <-> 32 slots).
// Threefry (sub=0) or s_nops (sub=1) cover asm-MFMA -> VALU read hazard.

typedef __attribute__((ext_vector_type(8))) short f16x8;
typedef __attribute__((ext_vector_type(4))) float f32x4;

struct __align__(16) Smem {
  unsigned short bfrag[2][4][4][4][8]; // [parity][q][kg][col][e] fp16, 2KB
  float nbuf[2][128];                  // [substep][row] 0.02-scaled noise, 1KB
  uint2 skeys[250];
  float red[4][4][2];                  // [wave][cond][o]
};

__device__ __forceinline__ void tfround(uint32_t& x0, uint32_t& x1, const int r) {
  x0 += x1;
  x1 = (x1 << r) | (x1 >> (32 - r));
  x1 ^= x0;
}

// JAX threefry2x32 (20 rounds)
__device__ __forceinline__ uint2 threefry(uint32_t k0, uint32_t k1, uint32_t c0, uint32_t c1) {
  uint32_t k2 = k0 ^ k1 ^ 0x1BD11BDAu;
  uint32_t x0 = c0 + k0, x1 = c1 + k1;
  tfround(x0,x1,13); tfround(x0,x1,15); tfround(x0,x1,26); tfround(x0,x1,6);
  x0 += k1; x1 += k2 + 1u;
  tfround(x0,x1,17); tfround(x0,x1,29); tfround(x0,x1,16); tfround(x0,x1,24);
  x0 += k2; x1 += k0 + 2u;
  tfround(x0,x1,13); tfround(x0,x1,15); tfround(x0,x1,26); tfround(x0,x1,6);
  x0 += k0; x1 += k1 + 3u;
  tfround(x0,x1,17); tfround(x0,x1,29); tfround(x0,x1,16); tfround(x0,x1,24);
  x0 += k1; x1 += k2 + 4u;
  tfround(x0,x1,13); tfround(x0,x1,15); tfround(x0,x1,26); tfround(x0,x1,6);
  x0 += k2; x1 += k0 + 5u;
  return make_uint2(x0, x1);
}

__device__ __forceinline__ float unit_from_bits(uint32_t bits) {
  return __uint_as_float((bits >> 9) | 0x3f800000u) - 1.0f;
}

// float -> fp16 bits, RNE (default HW mode for v_cvt_f16_f32)
__device__ __forceinline__ unsigned short f2h(float f) {
  _Float16 h = (_Float16)f;
  unsigned short u;
  __builtin_memcpy(&u, &h, 2);
  return u;
}

// MFMA accumulate in place, A from AGPR (fp16).
__device__ __forceinline__ void mfma_aa(f32x4& acc, const f16x8& a, const f16x8& b) {
  asm("v_mfma_f32_16x16x32_f16 %0, %1, %2, %0" : "+v"(acc) : "a"(a), "v"(b));
}
// Chain head: D = A*B + C (D fresh, no init movs).
__device__ __forceinline__ f32x4 mfma_c(const f16x8& a, const f16x8& b, const f32x4& c) {
  f32x4 d;
  asm("v_mfma_f32_16x16x32_f16 %0, %1, %2, %3" : "=&v"(d) : "a"(a), "v"(b), "v"(c));
  return d;
}

__global__ __launch_bounds__(256)
__attribute__((amdgpu_waves_per_eu(4, 8)))
void rnn_kernel(
    const float* __restrict__ x,
    const float* __restrict__ rec_w,
    const float* __restrict__ rec_b,
    const float* __restrict__ inp_w,
    const float* __restrict__ out_w,
    const float* __restrict__ mem_w,
    float* __restrict__ out) {
  __shared__ Smem sm;
  const int t = threadIdx.x;
  const int m = blockIdx.x;
  const int w = t >> 6;          // wave 0..3
  const int lane = t & 63;
  const int n = lane & 15;       // A-row / B-col / C-col index within tile
  const int kg = lane >> 4;      // k-group (0..3)
  const int c = n & 3;           // cond id
  const int t2sel = n >> 3;      // owned M-tile (0: rows +0..15, 1: +16..31)
  const int wrhalf = (n >> 2) & 1;  // 0 = fragment writer, 1 = duplicate

  // step keys
  if (t < 250) {
    int p = t / 50, s = t - p * 50;
    uint2 pk = threefry(0u, 42u, 0u, (uint32_t)p);
    sm.skeys[t] = threefry(pk.x, pk.y, 0u, (uint32_t)s);
  }
  // zero the fragment buffer: exactly 2KB = 256 threads x 8B
  {
    uint2* bz = reinterpret_cast<uint2*>(&sm.bfrag[0][0][0][0][0]);
    bz[t] = make_uint2(0u, 0u);
  }

  // --- W fragments (fp16, AGPR-destined): row = 32w+16*t2+n, k = 32q+8kg+e
  f16x8 whA[2][4];
  #pragma unroll
  for (int t2 = 0; t2 < 2; ++t2) {
    const int rowA = 32 * w + 16 * t2 + n;
    const float* gp = rec_w + (size_t)m * 16384 + (size_t)rowA * 128 + 8 * kg;
    #pragma unroll
    for (int q = 0; q < 4; ++q) {
      float4 f0 = *reinterpret_cast<const float4*>(gp + 32 * q);
      float4 f1 = *reinterpret_cast<const float4*>(gp + 32 * q + 4);
      float fv[8] = {f0.x, f0.y, f0.z, f0.w, f1.x, f1.y, f1.z, f1.w};
      f16x8 vh;
      #pragma unroll
      for (int e = 0; e < 8; ++e) vh[e] = (short)f2h(fv[e]);
      whA[t2][q] = vh;
    }
  }

  // per-lane x scalars (cond = c)
  const float xs0 = x[c * 4 + 0], xs1 = x[c * 4 + 1];
  const float xt0 = x[c * 4 + 2], xt1 = x[c * 4 + 3];

  // owned rows: rowU..rowU+3 (cond c)
  const int rowU = 32 * w + 4 * kg + 16 * t2sel;

  float rr[4] = {0.f, 0.f, 0.f, 0.f};
  float rs[4];

  __syncthreads();

  const uint32_t njbase = (uint32_t)(m * 128 + 32 * w + (lane & 31));

  for (int ph = 0; ph < 5; ++ph) {
    // ccv = bias + input drive for owned rows; seeds the MFMA C-init so pre
    // carries it exactly once. (Cols n>=4 get duplicate cc -> unused, fine.)
    f32x4 ccv;
    {
      float4 b4 = *reinterpret_cast<const float4*>(&rec_b[(size_t)m * 128 + rowU]);
      float cc[4] = {b4.x, b4.y, b4.z, b4.w};
      if (ph == 1 || ph == 3) {
        const float xa = (ph == 1) ? xs0 : xt0;
        const float xb = (ph == 1) ? xs1 : xt1;
        const float* ip = inp_w + ((size_t)m * 128 + rowU) * 2;
        float4 iA = *reinterpret_cast<const float4*>(ip);
        float4 iB = *reinterpret_cast<const float4*>(ip + 4);
        cc[0] += iA.x * xa + iA.y * xb;
        cc[1] += iA.z * xa + iA.w * xb;
        cc[2] += iB.x * xa + iB.y * xb;
        cc[3] += iB.z * xa + iB.w * xb;
      }
      #pragma unroll
      for (int k = 0; k < 4; ++k) ccv[k] = cc[k];
    }
    const bool phD = (ph == 2), phR = (ph == 4);
    #pragma unroll
    for (int k = 0; k < 4; ++k) rs[k] = 0.f;

    for (int sp = 0; sp < 25; ++sp) {
      #pragma unroll
      for (int sub = 0; sub < 2; ++sub) {
        // --- 2 independent 4-deep MFMA chains (one per M-tile); B[q]
        // consumed per-q so at most ~2 B fragments are live.
        const unsigned short* bp = &sm.bfrag[sub][0][kg][n & 3][0];
        f16x8 Bq = *reinterpret_cast<const f16x8*>(bp);
        f32x4 h0 = mfma_c(whA[0][0], Bq, ccv);
        f32x4 h1 = mfma_c(whA[1][0], Bq, ccv);
        #pragma unroll
        for (int q = 1; q < 4; ++q) {
          Bq = *reinterpret_cast<const f16x8*>(bp + q * 128);  // [q] stride
          mfma_aa(h0, whA[0][q], Bq);
          mfma_aa(h1, whA[1][q], Bq);
        }

        if (sub == 0) {
          // threefry fills the MFMA->read hazard window (~70 VALU instrs) and
          // overlaps the MFMA pipe. nbuf is wave-local; DS ops within a wave
          // are in-order, so the b128 reads below see these writes.
          uint2 key = sm.skeys[ph * 50 + 2 * sp + (lane >> 5)];
          uint2 bb = threefry(key.x, key.y, 0u, njbase);
          sm.nbuf[lane >> 5][32 * w + (lane & 31)] = 0.02f * unit_from_bits(bb.x ^ bb.y);
        } else {
          // inline-asm MFMA is invisible to the hazard recognizer: guard the
          // D->VALU read with explicit wait states.
          asm volatile("s_nop 7\n\ts_nop 3" ::);
        }

        // --- pre = acc[own tile] (cc already inside)
        float4 nz4 = *reinterpret_cast<const float4*>(&sm.nbuf[sub][rowU]);
        float nzv[4] = {nz4.x, nz4.y, nz4.z, nz4.w};
        #pragma unroll
        for (int k = 0; k < 4; ++k) {
          float pre = t2sel ? h1[k] : h0[k];
          float rl = fmaxf(pre, 0.f);
          rr[k] = fmaf(0.8f, rr[k], fmaf(0.2f, rl, nzv[k]));
        }
        if ((phD && ((sub == 0 && sp >= 13) || (sub == 1 && sp >= 12))) || phR) {
          #pragma unroll
          for (int k = 0; k < 4; ++k) rs[k] += rr[k];
        }

        // --- write next-step fragment: 32 writer lanes (wrhalf==0), each one
        // uint2 = 4 packed fp16. dest (kgw,c,e0) <-> (t2sel,kg,c) bijective.
        if (!wrhalf) {
          const int kgw = 2 * t2sel + (kg >> 1);
          const int e0 = 4 * (kg & 1);
          uint32_t p0 = ((uint32_t)f2h(rr[1]) << 16) | f2h(rr[0]);
          uint32_t p1 = ((uint32_t)f2h(rr[3]) << 16) | f2h(rr[2]);
          *reinterpret_cast<uint2*>(&sm.bfrag[sub ^ 1][w][kgw][c][e0]) =
              make_uint2(p0, p1);
        }
        __syncthreads();
      }
    }

    // --- phase-end projection (linear => project accumulated sums once)
    if (ph == 2 || ph == 4) {
      const float* pw = (ph == 2) ? mem_w : out_w;
      const float denom = (ph == 2) ? 25.0f : 50.0f;
      const int sel = (ph == 2) ? 0 : 1;
      float part[2];
      #pragma unroll
      for (int o = 0; o < 2; ++o) {
        float4 w4 = *reinterpret_cast<const float4*>(&pw[((size_t)m * 2 + o) * 128 + rowU]);
        part[o] = w4.x * rs[0] + w4.y * rs[1] + w4.z * rs[2] + w4.w * rs[3];
      }
      // reduce: xor8 merges t2 partners; xor16/32 merge kg. n&7 classes stay
      // separate, so the wrhalf duplicate lanes never double-count.
      #pragma unroll
      for (int o = 0; o < 2; ++o) {
        part[o] += __shfl_xor(part[o], 8, 64);
        part[o] += __shfl_xor(part[o], 16, 64);
        part[o] += __shfl_xor(part[o], 32, 64);
      }
      if (lane < 4) {
        sm.red[w][lane][0] = part[0];
        sm.red[w][lane][1] = part[1];
      }
      __syncthreads();
      if (t < 8) {
        int a = t >> 1, o = t & 1;
        float v = sm.red[0][a][o] + sm.red[1][a][o] + sm.red[2][a][o] + sm.red[3][a][o];
        out[(((size_t)sel * 4 + a) * 2048 + m) * 2 + o] = v / denom;
      }
      __syncthreads();
    }
  }
}

extern "C" void kernel_launch(void* const* d_in, const int* in_sizes, int n_in,
                              void* d_out, int out_size, void* d_ws, size_t ws_size,
                              hipStream_t stream) {
  (void)in_sizes; (void)n_in; (void)d_ws; (void)ws_size; (void)out_size;
  const float* x     = (const float*)d_in[0];
  const float* rec_w = (const float*)d_in[1];
  const float* rec_b = (const float*)d_in[2];
  const float* inp_w = (const float*)d_in[3];
  const float* out_w = (const float*)d_in[4];
  const float* mem_w = (const float*)d_in[5];
  rnn_kernel<<<2048, 256, 0, stream>>>(x, rec_w, rec_b, inp_w, out_w, mem_w, (float*)d_out);
}

// Round 13
// 337.156 us; speedup vs baseline: 1.5298x; 1.0183x over previous
//
#include <hip/hip_runtime.h>
#include <stdint.h>

// RNN ensemble: M=2048 models, N=128, A=4 conds, 5 phases x 50 steps.
// Block = 1 model, 4 waves. Wave w owns rows 32w..32w+31 (2 M-tiles).
// Single-pass FP16 matvec: pre[128x4] = W@r via v_mfma_f32_16x16x32_f16,
// B cols 0-3 = r (4 conds), fp32 accumulate, cc seeded in MFMA C-init.
// 8 W fragments pinned in AGPRs (32) via all-asm MFMA; 2 independent 4-deep
// chains. Threefry (sub=0) or s_nops (sub=1) cover the asm-MFMA read hazard.
// R13 = R12 with the cvt_pkrtz return-type compile fix (auto + memcpy).
// R12 VALU trims vs R11: cvt_pkrtz pack (6->2 instrs), k2 precomputed in
// skeys (uint4), v_pk_fma_f32 outer update + v_pk_add_f32 rs accumulate on
// paired rr regs, noise = fmaf(0.02,u,-0.02).

typedef __attribute__((ext_vector_type(8))) short f16x8;
typedef __attribute__((ext_vector_type(4))) float f32x4;
typedef __attribute__((ext_vector_type(2))) float f32x2;

struct __align__(16) Smem {
  unsigned short bfrag[2][4][4][4][8]; // [parity][q][kg][col][e] fp16, 2KB
  float nbuf[2][128];                  // [substep][row] 0.02-scaled noise, 1KB
  uint4 skeys[250];                    // (k0,k1,k2,-) per step, 4KB
  float red[4][4][2];                  // [wave][cond][o]
};

__device__ __forceinline__ void tfround(uint32_t& x0, uint32_t& x1, const int r) {
  x0 += x1;
  x1 = (x1 << r) | (x1 >> (32 - r));
  x1 ^= x0;
}

// JAX threefry2x32 (20 rounds), c0 = 0, k2 precomputed.
__device__ __forceinline__ uint2 threefry_k(uint32_t k0, uint32_t k1, uint32_t k2,
                                            uint32_t c1) {
  uint32_t x0 = k0, x1 = c1 + k1;
  tfround(x0,x1,13); tfround(x0,x1,15); tfround(x0,x1,26); tfround(x0,x1,6);
  x0 += k1; x1 += k2 + 1u;
  tfround(x0,x1,17); tfround(x0,x1,29); tfround(x0,x1,16); tfround(x0,x1,24);
  x0 += k2; x1 += k0 + 2u;
  tfround(x0,x1,13); tfround(x0,x1,15); tfround(x0,x1,26); tfround(x0,x1,6);
  x0 += k0; x1 += k1 + 3u;
  tfround(x0,x1,17); tfround(x0,x1,29); tfround(x0,x1,16); tfround(x0,x1,24);
  x0 += k1; x1 += k2 + 4u;
  tfround(x0,x1,13); tfround(x0,x1,15); tfround(x0,x1,26); tfround(x0,x1,6);
  x0 += k2; x1 += k0 + 5u;
  return make_uint2(x0, x1);
}

// float -> fp16 bits, RNE (W setup only)
__device__ __forceinline__ unsigned short f2h(float f) {
  _Float16 h = (_Float16)f;
  unsigned short u;
  __builtin_memcpy(&u, &h, 2);
  return u;
}
// packed RTZ f32x2 -> f16x2 (1 instr)
__device__ __forceinline__ uint32_t pkrtz(float a, float b) {
  auto h = __builtin_amdgcn_cvt_pkrtz(a, b);   // __fp16 ext_vector(2)
  uint32_t u;
  __builtin_memcpy(&u, &h, 4);
  return u;
}
// packed f32 FMA / ADD (VOP3P)
__device__ __forceinline__ f32x2 pk_fma(f32x2 a, f32x2 b, f32x2 c) {
  f32x2 d;
  asm("v_pk_fma_f32 %0, %1, %2, %3" : "=v"(d) : "v"(a), "v"(b), "v"(c));
  return d;
}
__device__ __forceinline__ f32x2 pk_add(f32x2 a, f32x2 b) {
  f32x2 d;
  asm("v_pk_add_f32 %0, %1, %2" : "=v"(d) : "v"(a), "v"(b));
  return d;
}
// MFMA accumulate in place, A from AGPR (fp16).
__device__ __forceinline__ void mfma_aa(f32x4& acc, const f16x8& a, const f16x8& b) {
  asm("v_mfma_f32_16x16x32_f16 %0, %1, %2, %0" : "+v"(acc) : "a"(a), "v"(b));
}
// Chain head: D = A*B + C (D fresh, no init movs).
__device__ __forceinline__ f32x4 mfma_c(const f16x8& a, const f16x8& b, const f32x4& c) {
  f32x4 d;
  asm("v_mfma_f32_16x16x32_f16 %0, %1, %2, %3" : "=&v"(d) : "a"(a), "v"(b), "v"(c));
  return d;
}

__global__ __launch_bounds__(256)
__attribute__((amdgpu_waves_per_eu(4, 8)))
void rnn_kernel(
    const float* __restrict__ x,
    const float* __restrict__ rec_w,
    const float* __restrict__ rec_b,
    const float* __restrict__ inp_w,
    const float* __restrict__ out_w,
    const float* __restrict__ mem_w,
    float* __restrict__ out) {
  __shared__ Smem sm;
  const int t = threadIdx.x;
  const int m = blockIdx.x;
  const int w = t >> 6;          // wave 0..3
  const int lane = t & 63;
  const int n = lane & 15;       // A-row / B-col / C-col index within tile
  const int kg = lane >> 4;      // k-group (0..3)
  const int c = n & 3;           // cond id
  const int t2sel = n >> 3;      // owned M-tile (0: rows +0..15, 1: +16..31)
  const int wrhalf = (n >> 2) & 1;  // 0 = fragment writer, 1 = duplicate

  // step keys (k2 precomputed)
  if (t < 250) {
    int p = t / 50, s = t - p * 50;
    uint2 pk = threefry_k(0u, 42u, 0u ^ 42u ^ 0x1BD11BDAu, (uint32_t)p);
    uint2 sk = threefry_k(pk.x, pk.y, pk.x ^ pk.y ^ 0x1BD11BDAu, (uint32_t)s);
    sm.skeys[t] = make_uint4(sk.x, sk.y, sk.x ^ sk.y ^ 0x1BD11BDAu, 0u);
  }
  // zero the fragment buffer: exactly 2KB = 256 threads x 8B
  {
    uint2* bz = reinterpret_cast<uint2*>(&sm.bfrag[0][0][0][0][0]);
    bz[t] = make_uint2(0u, 0u);
  }

  // --- W fragments (fp16, AGPR-destined): row = 32w+16*t2+n, k = 32q+8kg+e
  f16x8 whA[2][4];
  #pragma unroll
  for (int t2 = 0; t2 < 2; ++t2) {
    const int rowA = 32 * w + 16 * t2 + n;
    const float* gp = rec_w + (size_t)m * 16384 + (size_t)rowA * 128 + 8 * kg;
    #pragma unroll
    for (int q = 0; q < 4; ++q) {
      float4 f0 = *reinterpret_cast<const float4*>(gp + 32 * q);
      float4 f1 = *reinterpret_cast<const float4*>(gp + 32 * q + 4);
      float fv[8] = {f0.x, f0.y, f0.z, f0.w, f1.x, f1.y, f1.z, f1.w};
      f16x8 vh;
      #pragma unroll
      for (int e = 0; e < 8; ++e) vh[e] = (short)f2h(fv[e]);
      whA[t2][q] = vh;
    }
  }

  // per-lane x scalars (cond = c)
  const float xs0 = x[c * 4 + 0], xs1 = x[c * 4 + 1];
  const float xt0 = x[c * 4 + 2], xt1 = x[c * 4 + 3];

  // owned rows: rowU..rowU+3 (cond c)
  const int rowU = 32 * w + 4 * kg + 16 * t2sel;

  f32x2 rrA = {0.f, 0.f}, rrB = {0.f, 0.f};
  f32x2 rsA, rsB;
  const f32x2 c08 = {0.8f, 0.8f};

  __syncthreads();

  const uint32_t njbase = (uint32_t)(m * 128 + 32 * w + (lane & 31));

  for (int ph = 0; ph < 5; ++ph) {
    // ccv = bias + input drive for owned rows; seeds the MFMA C-init so pre
    // carries it exactly once. (Cols n>=4 get duplicate cc -> unused, fine.)
    f32x4 ccv;
    {
      float4 b4 = *reinterpret_cast<const float4*>(&rec_b[(size_t)m * 128 + rowU]);
      float cc[4] = {b4.x, b4.y, b4.z, b4.w};
      if (ph == 1 || ph == 3) {
        const float xa = (ph == 1) ? xs0 : xt0;
        const float xb = (ph == 1) ? xs1 : xt1;
        const float* ip = inp_w + ((size_t)m * 128 + rowU) * 2;
        float4 iA = *reinterpret_cast<const float4*>(ip);
        float4 iB = *reinterpret_cast<const float4*>(ip + 4);
        cc[0] += iA.x * xa + iA.y * xb;
        cc[1] += iA.z * xa + iA.w * xb;
        cc[2] += iB.x * xa + iB.y * xb;
        cc[3] += iB.z * xa + iB.w * xb;
      }
      #pragma unroll
      for (int k = 0; k < 4; ++k) ccv[k] = cc[k];
    }
    const bool phD = (ph == 2), phR = (ph == 4);
    rsA = (f32x2){0.f, 0.f};
    rsB = (f32x2){0.f, 0.f};

    for (int sp = 0; sp < 25; ++sp) {
      #pragma unroll
      for (int sub = 0; sub < 2; ++sub) {
        // --- 2 independent 4-deep MFMA chains (one per M-tile); B[q]
        // consumed per-q so at most ~2 B fragments are live.
        const unsigned short* bp = &sm.bfrag[sub][0][kg][n & 3][0];
        f16x8 Bq = *reinterpret_cast<const f16x8*>(bp);
        f32x4 h0 = mfma_c(whA[0][0], Bq, ccv);
        f32x4 h1 = mfma_c(whA[1][0], Bq, ccv);
        #pragma unroll
        for (int q = 1; q < 4; ++q) {
          Bq = *reinterpret_cast<const f16x8*>(bp + q * 128);  // [q] stride
          mfma_aa(h0, whA[0][q], Bq);
          mfma_aa(h1, whA[1][q], Bq);
        }

        if (sub == 0) {
          // threefry fills the MFMA->read hazard window (~65 VALU instrs) and
          // overlaps the MFMA pipe. nbuf is wave-local; DS ops within a wave
          // are in-order, so the b128 reads below see these writes.
          uint4 key = sm.skeys[ph * 50 + 2 * sp + (lane >> 5)];
          uint2 bb = threefry_k(key.x, key.y, key.z, njbase);
          uint32_t bits = bb.x ^ bb.y;
          float u = __uint_as_float((bits >> 9) | 0x3f800000u);
          sm.nbuf[lane >> 5][32 * w + (lane & 31)] = fmaf(0.02f, u, -0.02f);
        } else {
          // inline-asm MFMA is invisible to the hazard recognizer: guard the
          // D->VALU read with explicit wait states.
          asm volatile("s_nop 7\n\ts_nop 3" ::);
        }

        // --- pre = acc[own tile] (cc already inside)
        float4 nz4 = *reinterpret_cast<const float4*>(&sm.nbuf[sub][rowU]);
        float p0 = t2sel ? h1[0] : h0[0];
        float p1 = t2sel ? h1[1] : h0[1];
        float p2 = t2sel ? h1[2] : h0[2];
        float p3 = t2sel ? h1[3] : h0[3];
        f32x2 in0, in1;
        in0.x = fmaf(0.2f, fmaxf(p0, 0.f), nz4.x);
        in0.y = fmaf(0.2f, fmaxf(p1, 0.f), nz4.y);
        in1.x = fmaf(0.2f, fmaxf(p2, 0.f), nz4.z);
        in1.y = fmaf(0.2f, fmaxf(p3, 0.f), nz4.w);
        rrA = pk_fma(c08, rrA, in0);
        rrB = pk_fma(c08, rrB, in1);
        if ((phD && ((sub == 0 && sp >= 13) || (sub == 1 && sp >= 12))) || phR) {
          rsA = pk_add(rsA, rrA);
          rsB = pk_add(rsB, rrB);
        }

        // --- pack (all lanes, RTZ) & write next-step fragment (writer lanes)
        {
          uint32_t q0 = pkrtz(rrA.x, rrA.y);
          uint32_t q1 = pkrtz(rrB.x, rrB.y);
          if (!wrhalf) {
            const int kgw = 2 * t2sel + (kg >> 1);
            const int e0 = 4 * (kg & 1);
            *reinterpret_cast<uint2*>(&sm.bfrag[sub ^ 1][w][kgw][c][e0]) =
                make_uint2(q0, q1);
          }
        }
        __syncthreads();
      }
    }

    // --- phase-end projection (linear => project accumulated sums once)
    if (ph == 2 || ph == 4) {
      const float* pw = (ph == 2) ? mem_w : out_w;
      const float denom = (ph == 2) ? 25.0f : 50.0f;
      const int sel = (ph == 2) ? 0 : 1;
      float part[2];
      #pragma unroll
      for (int o = 0; o < 2; ++o) {
        float4 w4 = *reinterpret_cast<const float4*>(&pw[((size_t)m * 2 + o) * 128 + rowU]);
        part[o] = w4.x * rsA.x + w4.y * rsA.y + w4.z * rsB.x + w4.w * rsB.y;
      }
      // reduce: xor8 merges t2 partners; xor16/32 merge kg. n&7 classes stay
      // separate, so the wrhalf duplicate lanes never double-count.
      #pragma unroll
      for (int o = 0; o < 2; ++o) {
        part[o] += __shfl_xor(part[o], 8, 64);
        part[o] += __shfl_xor(part[o], 16, 64);
        part[o] += __shfl_xor(part[o], 32, 64);
      }
      if (lane < 4) {
        sm.red[w][lane][0] = part[0];
        sm.red[w][lane][1] = part[1];
      }
      __syncthreads();
      if (t < 8) {
        int a = t >> 1, o = t & 1;
        float v = sm.red[0][a][o] + sm.red[1][a][o] + sm.red[2][a][o] + sm.red[3][a][o];
        out[(((size_t)sel * 4 + a) * 2048 + m) * 2 + o] = v / denom;
      }
      __syncthreads();
    }
  }
}

extern "C" void kernel_launch(void* const* d_in, const int* in_sizes, int n_in,
                              void* d_out, int out_size, void* d_ws, size_t ws_size,
                              hipStream_t stream) {
  (void)in_sizes; (void)n_in; (void)d_ws; (void)ws_size; (void)out_size;
  const float* x     = (const float*)d_in[0];
  const float* rec_w = (const float*)d_in[1];
  const float* rec_b = (const float*)d_in[2];
  const float* inp_w = (const float*)d_in[3];
  const float* out_w = (const float*)d_in[4];
  const float* mem_w = (const float*)d_in[5];
  rnn_kernel<<<2048, 256, 0, stream>>>(x, rec_w, rec_b, inp_w, out_w, mem_w, (float*)d_out);
}

// Round 19
// 337.126 us; speedup vs baseline: 1.5299x; 1.0001x over previous
//
#include <hip/hip_runtime.h>
#include <stdint.h>

// RNN ensemble: M=2048 models, N=128, A=4 conds, 5 phases x 50 steps.
// Block = 1 model, 4 waves. Wave w owns rows 32w..32w+31 (2 M-tiles).
// Single-pass FP16 matvec: pre[128x4] = W@r via v_mfma_f32_16x16x32_f16,
// B cols 0-3 = r (4 conds), fp32 accumulate, cc seeded in MFMA C-init.
// 8 W fragments pinned in AGPRs (32) via all-asm MFMA; 2 independent 4-deep
// chains. Threefry (sub=0) or s_nops (sub=1) cover the asm-MFMA read hazard.
// R19 = R13 VERBATIM (last passing: 337us, absmax 1.678e-4). Rounds 14-18
// explored 1-wave barrier-free and 2-model-per-block structures; all five
// produced deterministic numeric deviations (4.5e-4..1.95e-3) despite
// operation-identical per-trajectory math audits, and the hazard theory was
// refuted by R17-vs-R18 A/B. Re-anchoring on the proven binary.

typedef __attribute__((ext_vector_type(8))) short f16x8;
typedef __attribute__((ext_vector_type(4))) float f32x4;
typedef __attribute__((ext_vector_type(2))) float f32x2;

struct __align__(16) Smem {
  unsigned short bfrag[2][4][4][4][8]; // [parity][q][kg][col][e] fp16, 2KB
  float nbuf[2][128];                  // [substep][row] 0.02-scaled noise, 1KB
  uint4 skeys[250];                    // (k0,k1,k2,-) per step, 4KB
  float red[4][4][2];                  // [wave][cond][o]
};

__device__ __forceinline__ void tfround(uint32_t& x0, uint32_t& x1, const int r) {
  x0 += x1;
  x1 = (x1 << r) | (x1 >> (32 - r));
  x1 ^= x0;
}

// JAX threefry2x32 (20 rounds), c0 = 0, k2 precomputed.
__device__ __forceinline__ uint2 threefry_k(uint32_t k0, uint32_t k1, uint32_t k2,
                                            uint32_t c1) {
  uint32_t x0 = k0, x1 = c1 + k1;
  tfround(x0,x1,13); tfround(x0,x1,15); tfround(x0,x1,26); tfround(x0,x1,6);
  x0 += k1; x1 += k2 + 1u;
  tfround(x0,x1,17); tfround(x0,x1,29); tfround(x0,x1,16); tfround(x0,x1,24);
  x0 += k2; x1 += k0 + 2u;
  tfround(x0,x1,13); tfround(x0,x1,15); tfround(x0,x1,26); tfround(x0,x1,6);
  x0 += k0; x1 += k1 + 3u;
  tfround(x0,x1,17); tfround(x0,x1,29); tfround(x0,x1,16); tfround(x0,x1,24);
  x0 += k1; x1 += k2 + 4u;
  tfround(x0,x1,13); tfround(x0,x1,15); tfround(x0,x1,26); tfround(x0,x1,6);
  x0 += k2; x1 += k0 + 5u;
  return make_uint2(x0, x1);
}

// float -> fp16 bits, RNE (W setup only)
__device__ __forceinline__ unsigned short f2h(float f) {
  _Float16 h = (_Float16)f;
  unsigned short u;
  __builtin_memcpy(&u, &h, 2);
  return u;
}
// packed RTZ f32x2 -> f16x2 (1 instr)
__device__ __forceinline__ uint32_t pkrtz(float a, float b) {
  auto h = __builtin_amdgcn_cvt_pkrtz(a, b);   // __fp16 ext_vector(2)
  uint32_t u;
  __builtin_memcpy(&u, &h, 4);
  return u;
}
// packed f32 FMA / ADD (VOP3P)
__device__ __forceinline__ f32x2 pk_fma(f32x2 a, f32x2 b, f32x2 c) {
  f32x2 d;
  asm("v_pk_fma_f32 %0, %1, %2, %3" : "=v"(d) : "v"(a), "v"(b), "v"(c));
  return d;
}
__device__ __forceinline__ f32x2 pk_add(f32x2 a, f32x2 b) {
  f32x2 d;
  asm("v_pk_add_f32 %0, %1, %2" : "=v"(d) : "v"(a), "v"(b));
  return d;
}
// MFMA accumulate in place, A from AGPR (fp16).
__device__ __forceinline__ void mfma_aa(f32x4& acc, const f16x8& a, const f16x8& b) {
  asm("v_mfma_f32_16x16x32_f16 %0, %1, %2, %0" : "+v"(acc) : "a"(a), "v"(b));
}
// Chain head: D = A*B + C (D fresh, no init movs).
__device__ __forceinline__ f32x4 mfma_c(const f16x8& a, const f16x8& b, const f32x4& c) {
  f32x4 d;
  asm("v_mfma_f32_16x16x32_f16 %0, %1, %2, %3" : "=&v"(d) : "a"(a), "v"(b), "v"(c));
  return d;
}

__global__ __launch_bounds__(256)
__attribute__((amdgpu_waves_per_eu(4, 8)))
void rnn_kernel(
    const float* __restrict__ x,
    const float* __restrict__ rec_w,
    const float* __restrict__ rec_b,
    const float* __restrict__ inp_w,
    const float* __restrict__ out_w,
    const float* __restrict__ mem_w,
    float* __restrict__ out) {
  __shared__ Smem sm;
  const int t = threadIdx.x;
  const int m = blockIdx.x;
  const int w = t >> 6;          // wave 0..3
  const int lane = t & 63;
  const int n = lane & 15;       // A-row / B-col / C-col index within tile
  const int kg = lane >> 4;      // k-group (0..3)
  const int c = n & 3;           // cond id
  const int t2sel = n >> 3;      // owned M-tile (0: rows +0..15, 1: +16..31)
  const int wrhalf = (n >> 2) & 1;  // 0 = fragment writer, 1 = duplicate

  // step keys (k2 precomputed)
  if (t < 250) {
    int p = t / 50, s = t - p * 50;
    uint2 pk = threefry_k(0u, 42u, 0u ^ 42u ^ 0x1BD11BDAu, (uint32_t)p);
    uint2 sk = threefry_k(pk.x, pk.y, pk.x ^ pk.y ^ 0x1BD11BDAu, (uint32_t)s);
    sm.skeys[t] = make_uint4(sk.x, sk.y, sk.x ^ sk.y ^ 0x1BD11BDAu, 0u);
  }
  // zero the fragment buffer: exactly 2KB = 256 threads x 8B
  {
    uint2* bz = reinterpret_cast<uint2*>(&sm.bfrag[0][0][0][0][0]);
    bz[t] = make_uint2(0u, 0u);
  }

  // --- W fragments (fp16, AGPR-destined): row = 32w+16*t2+n, k = 32q+8kg+e
  f16x8 whA[2][4];
  #pragma unroll
  for (int t2 = 0; t2 < 2; ++t2) {
    const int rowA = 32 * w + 16 * t2 + n;
    const float* gp = rec_w + (size_t)m * 16384 + (size_t)rowA * 128 + 8 * kg;
    #pragma unroll
    for (int q = 0; q < 4; ++q) {
      float4 f0 = *reinterpret_cast<const float4*>(gp + 32 * q);
      float4 f1 = *reinterpret_cast<const float4*>(gp + 32 * q + 4);
      float fv[8] = {f0.x, f0.y, f0.z, f0.w, f1.x, f1.y, f1.z, f1.w};
      f16x8 vh;
      #pragma unroll
      for (int e = 0; e < 8; ++e) vh[e] = (short)f2h(fv[e]);
      whA[t2][q] = vh;
    }
  }

  // per-lane x scalars (cond = c)
  const float xs0 = x[c * 4 + 0], xs1 = x[c * 4 + 1];
  const float xt0 = x[c * 4 + 2], xt1 = x[c * 4 + 3];

  // owned rows: rowU..rowU+3 (cond c)
  const int rowU = 32 * w + 4 * kg + 16 * t2sel;

  f32x2 rrA = {0.f, 0.f}, rrB = {0.f, 0.f};
  f32x2 rsA, rsB;
  const f32x2 c08 = {0.8f, 0.8f};

  __syncthreads();

  const uint32_t njbase = (uint32_t)(m * 128 + 32 * w + (lane & 31));

  for (int ph = 0; ph < 5; ++ph) {
    // ccv = bias + input drive for owned rows; seeds the MFMA C-init so pre
    // carries it exactly once. (Cols n>=4 get duplicate cc -> unused, fine.)
    f32x4 ccv;
    {
      float4 b4 = *reinterpret_cast<const float4*>(&rec_b[(size_t)m * 128 + rowU]);
      float cc[4] = {b4.x, b4.y, b4.z, b4.w};
      if (ph == 1 || ph == 3) {
        const float xa = (ph == 1) ? xs0 : xt0;
        const float xb = (ph == 1) ? xs1 : xt1;
        const float* ip = inp_w + ((size_t)m * 128 + rowU) * 2;
        float4 iA = *reinterpret_cast<const float4*>(ip);
        float4 iB = *reinterpret_cast<const float4*>(ip + 4);
        cc[0] += iA.x * xa + iA.y * xb;
        cc[1] += iA.z * xa + iA.w * xb;
        cc[2] += iB.x * xa + iB.y * xb;
        cc[3] += iB.z * xa + iB.w * xb;
      }
      #pragma unroll
      for (int k = 0; k < 4; ++k) ccv[k] = cc[k];
    }
    const bool phD = (ph == 2), phR = (ph == 4);
    rsA = (f32x2){0.f, 0.f};
    rsB = (f32x2){0.f, 0.f};

    for (int sp = 0; sp < 25; ++sp) {
      #pragma unroll
      for (int sub = 0; sub < 2; ++sub) {
        // --- 2 independent 4-deep MFMA chains (one per M-tile); B[q]
        // consumed per-q so at most ~2 B fragments are live.
        const unsigned short* bp = &sm.bfrag[sub][0][kg][n & 3][0];
        f16x8 Bq = *reinterpret_cast<const f16x8*>(bp);
        f32x4 h0 = mfma_c(whA[0][0], Bq, ccv);
        f32x4 h1 = mfma_c(whA[1][0], Bq, ccv);
        #pragma unroll
        for (int q = 1; q < 4; ++q) {
          Bq = *reinterpret_cast<const f16x8*>(bp + q * 128);  // [q] stride
          mfma_aa(h0, whA[0][q], Bq);
          mfma_aa(h1, whA[1][q], Bq);
        }

        if (sub == 0) {
          // threefry fills the MFMA->read hazard window (~65 VALU instrs) and
          // overlaps the MFMA pipe. nbuf is wave-local; DS ops within a wave
          // are in-order, so the b128 reads below see these writes.
          uint4 key = sm.skeys[ph * 50 + 2 * sp + (lane >> 5)];
          uint2 bb = threefry_k(key.x, key.y, key.z, njbase);
          uint32_t bits = bb.x ^ bb.y;
          float u = __uint_as_float((bits >> 9) | 0x3f800000u);
          sm.nbuf[lane >> 5][32 * w + (lane & 31)] = fmaf(0.02f, u, -0.02f);
        } else {
          // inline-asm MFMA is invisible to the hazard recognizer: guard the
          // D->VALU read with explicit wait states.
          asm volatile("s_nop 7\n\ts_nop 3" ::);
        }

        // --- pre = acc[own tile] (cc already inside)
        float4 nz4 = *reinterpret_cast<const float4*>(&sm.nbuf[sub][rowU]);
        float p0 = t2sel ? h1[0] : h0[0];
        float p1 = t2sel ? h1[1] : h0[1];
        float p2 = t2sel ? h1[2] : h0[2];
        float p3 = t2sel ? h1[3] : h0[3];
        f32x2 in0, in1;
        in0.x = fmaf(0.2f, fmaxf(p0, 0.f), nz4.x);
        in0.y = fmaf(0.2f, fmaxf(p1, 0.f), nz4.y);
        in1.x = fmaf(0.2f, fmaxf(p2, 0.f), nz4.z);
        in1.y = fmaf(0.2f, fmaxf(p3, 0.f), nz4.w);
        rrA = pk_fma(c08, rrA, in0);
        rrB = pk_fma(c08, rrB, in1);
        if ((phD && ((sub == 0 && sp >= 13) || (sub == 1 && sp >= 12))) || phR) {
          rsA = pk_add(rsA, rrA);
          rsB = pk_add(rsB, rrB);
        }

        // --- pack (all lanes, RTZ) & write next-step fragment (writer lanes)
        {
          uint32_t q0 = pkrtz(rrA.x, rrA.y);
          uint32_t q1 = pkrtz(rrB.x, rrB.y);
          if (!wrhalf) {
            const int kgw = 2 * t2sel + (kg >> 1);
            const int e0 = 4 * (kg & 1);
            *reinterpret_cast<uint2*>(&sm.bfrag[sub ^ 1][w][kgw][c][e0]) =
                make_uint2(q0, q1);
          }
        }
        __syncthreads();
      }
    }

    // --- phase-end projection (linear => project accumulated sums once)
    if (ph == 2 || ph == 4) {
      const float* pw = (ph == 2) ? mem_w : out_w;
      const float denom = (ph == 2) ? 25.0f : 50.0f;
      const int sel = (ph == 2) ? 0 : 1;
      float part[2];
      #pragma unroll
      for (int o = 0; o < 2; ++o) {
        float4 w4 = *reinterpret_cast<const float4*>(&pw[((size_t)m * 2 + o) * 128 + rowU]);
        part[o] = w4.x * rsA.x + w4.y * rsA.y + w4.z * rsB.x + w4.w * rsB.y;
      }
      // reduce: xor8 merges t2 partners; xor16/32 merge kg. n&7 classes stay
      // separate, so the wrhalf duplicate lanes never double-count.
      #pragma unroll
      for (int o = 0; o < 2; ++o) {
        part[o] += __shfl_xor(part[o], 8, 64);
        part[o] += __shfl_xor(part[o], 16, 64);
        part[o] += __shfl_xor(part[o], 32, 64);
      }
      if (lane < 4) {
        sm.red[w][lane][0] = part[0];
        sm.red[w][lane][1] = part[1];
      }
      __syncthreads();
      if (t < 8) {
        int a = t >> 1, o = t & 1;
        float v = sm.red[0][a][o] + sm.red[1][a][o] + sm.red[2][a][o] + sm.red[3][a][o];
        out[(((size_t)sel * 4 + a) * 2048 + m) * 2 + o] = v / denom;
      }
      __syncthreads();
    }
  }
}

extern "C" void kernel_launch(void* const* d_in, const int* in_sizes, int n_in,
                              void* d_out, int out_size, void* d_ws, size_t ws_size,
                              hipStream_t stream) {
  (void)in_sizes; (void)n_in; (void)d_ws; (void)ws_size; (void)out_size;
  const float* x     = (const float*)d_in[0];
  const float* rec_w = (const float*)d_in[1];
  const float* rec_b = (const float*)d_in[2];
  const float* inp_w = (const float*)d_in[3];
  const float* out_w = (const float*)d_in[4];
  const float* mem_w = (const float*)d_in[5];
  rnn_kernel<<<2048, 256, 0, stream>>>(x, rec_w, rec_b, inp_w, out_w, mem_w, (float*)d_out);
}